// Round 4
// baseline (276.254 us; speedup 1.0000x reference)
//
#include <hip/hip_runtime.h>

// ---------------------------------------------------------------------------
// GuidedAttentionL1Loss on MI355X — R3: fused, LDS-staged, 2 waves/segment.
// loss = nll + (ALPHA/2)*sum|params| + (BETA/2)*mean_b( sum_b (y-r)^2 / L_b )
// sum(y-r)^2 = sum y^2 - 2*sum(y*rh)/den + sum(rh^2)/den^2, den = sum(rh)+1e-6
// vs R2: no per-thread register array (it spilled to scratch: VGPR=48,
// 103us). y staged in LDS float4 region per segment; 2 waves/segment for
// 2x wave parallelism; L1/NLL blocks scheduled before seg blocks.
// ---------------------------------------------------------------------------

constexpr float INV_SQRT_2PI = 0.39894228040143267794f;
constexpr int L1_BLOCKS = 128;
constexpr int PRE_BLOCKS = L1_BLOCKS + 1;   // + 1 NLL block

// ws layout (bytes):
//   0:    unsigned counter (memset to 0 each launch)
//   512:  double nllsum
//   1024: float l1part[L1_BLOCKS]
//   2048: float segpart[Bn]

__global__ __launch_bounds__(256) void fused_kernel(
    const float* __restrict__ logits, const float* __restrict__ params,
    const float* __restrict__ attn, const int* __restrict__ labels,
    const int* __restrict__ lengths, int P, int Bn, int nblocks,
    unsigned* __restrict__ counter, double* __restrict__ nllsum,
    float* __restrict__ l1part, float* __restrict__ segpart,
    float* __restrict__ out) {
  const int tid = threadIdx.x, lane = tid & 63, wv = tid >> 6;
  const int bid = blockIdx.x;
  __shared__ float4 s_y4[2][768];          // 24 KB: y staging, 2 segments
  __shared__ float s_redA[2][2][2];        // pass-A partials per (seg, half)
  __shared__ float s_redB[2][2][4];        // pass-B partials
  __shared__ float s_l1[4];
  __shared__ double s_fin[4][2];
  __shared__ int s_last;

  if (bid < L1_BLOCKS) {
    // ---------------- L1: sum |params| --------------------------------------
    const float4* p4 = (const float4*)params;
    int n4 = P >> 2;
    float s = 0.f;
    for (int i = (bid << 8) + tid; i < n4; i += (L1_BLOCKS << 8)) {
      float4 v = p4[i];
      s += (fabsf(v.x) + fabsf(v.y)) + (fabsf(v.z) + fabsf(v.w));
    }
    if (bid == 0) {  // tail (empty when P%4==0)
      for (int i = (n4 << 2) + tid; i < P; i += 256) s += fabsf(params[i]);
    }
#pragma unroll
    for (int off = 32; off; off >>= 1) s += __shfl_xor(s, off, 64);
    if (lane == 0) s_l1[wv] = s;
    __syncthreads();
    if (tid == 0) l1part[bid] = (s_l1[0] + s_l1[1]) + (s_l1[2] + s_l1[3]);
  } else if (bid == L1_BLOCKS) {
    // ---------------- NLL ---------------------------------------------------
    double s = 0.0;
    const float2* lg2 = (const float2*)logits;
    for (int r = tid; r < Bn; r += 256) {
      float2 lg = lg2[r];
      float m = fmaxf(lg.x, lg.y);
      float lse = m + logf(expf(lg.x - m) + expf(lg.y - m));
      s += (double)(lse - ((labels[r] == 1) ? lg.y : lg.x));
    }
#pragma unroll
    for (int off = 32; off; off >>= 1) s += __shfl_down(s, off, 64);
    if (lane == 0) s_fin[wv][0] = s;
    __syncthreads();
    if (tid == 0)
      *nllsum = (s_fin[0][0] + s_fin[1][0]) + (s_fin[2][0] + s_fin[3][0]);
  } else {
    // ---------------- segment penalty: 2 waves per segment ------------------
    int si = wv >> 1;                  // segment slot within block (0/1)
    int h = wv & 1;                    // which half-wave of the segment
    int wid = (bid - PRE_BLOCKS) * 2 + si;
    bool valid = wid < Bn;
    int start = 0, L = 1;
    if (valid) {
      // exclusive start = sum lengths[0..wid) via int4 mini-scan (L1-hot)
      const int4* l4 = (const int4*)lengths;
      int nq = wid >> 2, sacc = 0;
      for (int q = lane; q < nq; q += 64) {
        int4 v = l4[q];
        sacc += (v.x + v.y) + (v.z + v.w);
      }
      if (lane < (wid & 3)) sacc += lengths[(wid & ~3) + lane];
#pragma unroll
      for (int off = 32; off; off >>= 1) sacc += __shfl_xor(sacc, off, 64);
      start = sacc;
      L = lengths[wid];
    }
    float invL = 1.0f / (float)L;
    const float* a = attn + start;
    int head = (4 - (start & 3)) & 3;  // peel to 16B alignment
    if (head > L) head = L;
    int nb = (L - head) >> 2;          // aligned quads (<= 768)
    int tail = L - head - (nb << 2);
    const float4* a4 = (const float4*)(a + head);

    // ---- pass A: read y once, stage in LDS, accumulate y-moments ----
    float sy = 0.f, sxy = 0.f, syy = 0.f;
    float yh = 0.f, yt = 0.f;
    int ih = -1, it = -1;
    if (valid && h == 0 && lane < head) {
      ih = lane; yh = a[ih];
      float x = (float)(ih + 1) * invL;
      sy += yh; sxy = fmaf(x, yh, sxy); syy = fmaf(yh, yh, syy);
    }
    if (valid && h == 1 && lane < tail) {
      it = head + (nb << 2) + lane; yt = a[it];
      float x = (float)(it + 1) * invL;
      sy += yt; sxy = fmaf(x, yt, sxy); syy = fmaf(yt, yt, syy);
    }
    if (valid) {
      for (int q = lane + (h << 6); q < nb; q += 128) {
        float4 v = a4[q];
        s_y4[si][q] = v;
        float xb = (float)(head + (q << 2) + 1) * invL;
        sy += (v.x + v.y) + (v.z + v.w);
        sxy = fmaf(xb, v.x, sxy);
        sxy = fmaf(xb + invL, v.y, sxy);
        sxy = fmaf(xb + 2.f * invL, v.z, sxy);
        sxy = fmaf(xb + 3.f * invL, v.w, sxy);
        syy = fmaf(v.x, v.x, fmaf(v.y, v.y, fmaf(v.z, v.z, fmaf(v.w, v.w, syy))));
      }
    }
#pragma unroll
    for (int off = 32; off; off >>= 1) {
      sy += __shfl_xor(sy, off, 64);
      sxy += __shfl_xor(sxy, off, 64);
    }
    if (lane == 0) { s_redA[si][h][0] = sy; s_redA[si][h][1] = sxy; }
    __syncthreads();
    float tot_y = s_redA[si][0][0] + s_redA[si][1][0];
    float tot_xy = s_redA[si][0][1] + s_redA[si][1][1];
    float mean = tot_xy / tot_y;                 // NaN for invalid, unused
    int lab = valid ? labels[wid] : 0;
    float inv_std = (lab == 1) ? (float)L : (float)L * 0.001f;
    float inv_norm = INV_SQRT_2PI * inv_std;
    float dz = invL * inv_std;

    // ---- pass B: y from LDS (own writes), rh analytic ----
    float sr = 0.f, syr = 0.f, srr = 0.f;
    if (ih >= 0) {
      float z = ((float)(ih + 1) * invL - mean) * inv_std;
      float r = expf(-0.5f * z * z) * inv_norm;
      sr += r; syr = fmaf(yh, r, syr); srr = fmaf(r, r, srr);
    }
    if (it >= 0) {
      float z = ((float)(it + 1) * invL - mean) * inv_std;
      float r = expf(-0.5f * z * z) * inv_norm;
      sr += r; syr = fmaf(yt, r, syr); srr = fmaf(r, r, srr);
    }
    if (valid) {
      for (int q = lane + (h << 6); q < nb; q += 128) {
        float4 v = s_y4[si][q];
        float z0 = ((float)(head + (q << 2) + 1) * invL - mean) * inv_std;
        float z1 = z0 + dz, z2 = z1 + dz, z3 = z2 + dz;
        float r0 = expf(-0.5f * z0 * z0) * inv_norm;
        float r1 = expf(-0.5f * z1 * z1) * inv_norm;
        float r2 = expf(-0.5f * z2 * z2) * inv_norm;
        float r3 = expf(-0.5f * z3 * z3) * inv_norm;
        sr += (r0 + r1) + (r2 + r3);
        syr = fmaf(v.x, r0, fmaf(v.y, r1, fmaf(v.z, r2, fmaf(v.w, r3, syr))));
        srr = fmaf(r0, r0, fmaf(r1, r1, fmaf(r2, r2, fmaf(r3, r3, srr))));
      }
    }
#pragma unroll
    for (int off = 32; off; off >>= 1) {
      syy += __shfl_xor(syy, off, 64);
      sr += __shfl_xor(sr, off, 64);
      syr += __shfl_xor(syr, off, 64);
      srr += __shfl_xor(srr, off, 64);
    }
    if (lane == 0) {
      s_redB[si][h][0] = syy; s_redB[si][h][1] = sr;
      s_redB[si][h][2] = syr; s_redB[si][h][3] = srr;
    }
    __syncthreads();
    if (valid && h == 0 && lane == 0) {
      float tyy = s_redB[si][0][0] + s_redB[si][1][0];
      float tsr = s_redB[si][0][1] + s_redB[si][1][1];
      float tyr = s_redB[si][0][2] + s_redB[si][1][2];
      float trr = s_redB[si][0][3] + s_redB[si][1][3];
      float inv_den = 1.0f / (tsr + 1e-6f);
      float d2 = tyy - 2.0f * tyr * inv_den + trr * (inv_den * inv_den);
      segpart[wid] = d2 * invL;
    }
  }

  // ---------------- completion counter; last block finalizes ----------------
  __threadfence();
  __syncthreads();
  if (tid == 0) {
    unsigned old = atomicAdd(counter, 1u);
    s_last = (old == (unsigned)(nblocks - 1)) ? 1 : 0;
  }
  __syncthreads();
  if (s_last) {
    __threadfence();
    double accS = 0.0, accL = 0.0;
    for (int j = tid; j < Bn; j += 256) accS += (double)segpart[j];
    for (int j = tid; j < L1_BLOCKS; j += 256) accL += (double)l1part[j];
#pragma unroll
    for (int off = 32; off; off >>= 1) {
      accS += __shfl_down(accS, off, 64);
      accL += __shfl_down(accL, off, 64);
    }
    if (lane == 0) { s_fin[wv][0] = accS; s_fin[wv][1] = accL; }
    __syncthreads();
    if (tid == 0) {
      double segsum = (s_fin[0][0] + s_fin[1][0]) + (s_fin[2][0] + s_fin[3][0]);
      double l1 = (s_fin[0][1] + s_fin[1][1]) + (s_fin[2][1] + s_fin[3][1]);
      double nll = *nllsum / (double)Bn;
      double loss = nll + 5e-4 * l1 + 0.05 * (segsum / (double)Bn);
      out[0] = (float)loss;
      out[1] = (float)nll;
    }
  }
}

extern "C" void kernel_launch(void* const* d_in, const int* in_sizes, int n_in,
                              void* d_out, int out_size, void* d_ws, size_t ws_size,
                              hipStream_t stream) {
  const float* logits  = (const float*)d_in[0];
  const float* params  = (const float*)d_in[1];
  const float* attn    = (const float*)d_in[2];
  const int*   labels  = (const int*)d_in[3];
  const int*   lengths = (const int*)d_in[4];
  // d_in[5] (seg_ids) unused: starts recomputed from lengths per wave.

  int Bn = in_sizes[3];
  int P  = in_sizes[1];
  int segBlocks = (Bn + 1) / 2;            // 2 segments per block

  unsigned* counter = (unsigned*)d_ws;
  double*   nllsum  = (double*)((char*)d_ws + 512);
  float*    l1part  = (float*)((char*)d_ws + 1024);
  float*    segpart = (float*)((char*)d_ws + 2048);

  hipMemsetAsync(d_ws, 0, 64, stream);     // zero completion counter

  int nblocks = PRE_BLOCKS + segBlocks;
  hipLaunchKernelGGL(fused_kernel, dim3(nblocks), dim3(256), 0, stream,
                     logits, params, attn, labels, lengths, P, Bn, nblocks,
                     counter, nllsum, l1part, segpart, (float*)d_out);
}

// Round 5
// 115.994 us; speedup vs baseline: 2.3816x; 2.3816x over previous
//
#include <hip/hip_runtime.h>

// ---------------------------------------------------------------------------
// GuidedAttentionL1Loss on MI355X — R4: back to R1's winning shape.
// loss = nll + (ALPHA/2)*sum|params| + (BETA/2)*mean_b( sum_b (y-r)^2 / L_b )
// sum(y-r)^2 = sum y^2 - 2*sum(y*rh)/den + sum(rh^2)/den^2, den = sum(rh)+1e-6
// Lessons: R2 reg-array spilled (scratch), R3 LDS+barriers+fence serialized.
// R4: wave-per-segment, NO barriers/LDS/atomics in hot path; float4 loads
// with 2x unroll (R1's defect was 64 scalar latency-exposed iters/wave);
// attn re-read in pass B is L3-hot (FETCH 19MB < 33.5MB proves residency).
// ---------------------------------------------------------------------------

constexpr float INV_SQRT_2PI = 0.39894228040143267794f;
constexpr int L1_BLOCKS = 512;

// ws layout (bytes) — every slot written before read, no zeroing needed:
//   0:     float segpart[4096]
//   16384: float l1part[L1_BLOCKS*4]
//   24576: float nllpart[4]

__global__ __launch_bounds__(256) void main_kernel(
    const float* __restrict__ logits, const float* __restrict__ params,
    const float* __restrict__ attn, const int* __restrict__ labels,
    const int* __restrict__ lengths, int P, int Bn, int segBlocks,
    float* __restrict__ segpart, float* __restrict__ l1part,
    float* __restrict__ nllpart) {
  const int tid = threadIdx.x, lane = tid & 63, wv = tid >> 6;
  const int bid = blockIdx.x;

  if (bid < segBlocks) {
    // ---------------- segment penalty: one wave per segment, no barriers ----
    int wid = (bid << 2) + wv;
    if (wid >= Bn) return;

    // exclusive start = sum lengths[0..wid) via int4 mini-scan (L2-hot)
    int sacc = 0;
    const int4* l4 = (const int4*)lengths;
    int nq = wid >> 2;
    for (int q = lane; q < nq; q += 64) {
      int4 v = l4[q];
      sacc += (v.x + v.y) + (v.z + v.w);
    }
    if (lane < (wid & 3)) sacc += lengths[(wid & ~3) + lane];
#pragma unroll
    for (int off = 32; off; off >>= 1) sacc += __shfl_xor(sacc, off, 64);
    int start = sacc;
    int L = lengths[wid];
    int lab = labels[wid];

    const float* a = attn + start;
    float invL = 1.0f / (float)L;
    int head = (4 - (start & 3)) & 3;   // peel to 16B alignment
    if (head > L) head = L;
    int nb = (L - head) >> 2;           // aligned float4 quads (<= 768)
    int tail = L - head - (nb << 2);
    const float4* a4 = (const float4*)(a + head);

    // ---- pass A: y-moments, float4 x2-unrolled (2 loads in flight) ----
    float sy = 0.f, sxy = 0.f, syy = 0.f;
    if (lane < head) {
      float y = a[lane];
      float x = (float)(lane + 1) * invL;
      sy += y; sxy = fmaf(x, y, sxy); syy = fmaf(y, y, syy);
    }
    if (lane < tail) {
      int i = head + (nb << 2) + lane;
      float y = a[i];
      float x = (float)(i + 1) * invL;
      sy += y; sxy = fmaf(x, y, sxy); syy = fmaf(y, y, syy);
    }
    for (int q = lane; q < nb; q += 128) {
      float4 v0 = a4[q];
      int q1 = q + 64;
      bool g1 = q1 < nb;
      float4 v1;
      if (g1) v1 = a4[q1];
      {
        float x0 = (float)(head + (q << 2) + 1) * invL;
        sy += (v0.x + v0.y) + (v0.z + v0.w);
        sxy = fmaf(x0, v0.x, fmaf(x0 + invL, v0.y,
              fmaf(x0 + 2.f * invL, v0.z, fmaf(x0 + 3.f * invL, v0.w, sxy))));
        syy = fmaf(v0.x, v0.x, fmaf(v0.y, v0.y,
              fmaf(v0.z, v0.z, fmaf(v0.w, v0.w, syy))));
      }
      if (g1) {
        float x0 = (float)(head + (q1 << 2) + 1) * invL;
        sy += (v1.x + v1.y) + (v1.z + v1.w);
        sxy = fmaf(x0, v1.x, fmaf(x0 + invL, v1.y,
              fmaf(x0 + 2.f * invL, v1.z, fmaf(x0 + 3.f * invL, v1.w, sxy))));
        syy = fmaf(v1.x, v1.x, fmaf(v1.y, v1.y,
              fmaf(v1.z, v1.z, fmaf(v1.w, v1.w, syy))));
      }
    }
#pragma unroll
    for (int off = 32; off; off >>= 1) {
      sy  += __shfl_xor(sy, off, 64);
      sxy += __shfl_xor(sxy, off, 64);
    }
    float mean = sxy / sy;
    float inv_std = (lab == 1) ? (float)L : (float)L * 0.001f;
    float inv_norm = INV_SQRT_2PI * inv_std;
    float dz = invL * inv_std;

    // ---- pass B: re-read y (L2/L3-hot), rh moments, same unroll ----
    float sr = 0.f, syr = 0.f, srr = 0.f;
    if (lane < head) {
      float y = a[lane];
      float z = ((float)(lane + 1) * invL - mean) * inv_std;
      float r = expf(-0.5f * z * z) * inv_norm;
      sr += r; syr = fmaf(y, r, syr); srr = fmaf(r, r, srr);
    }
    if (lane < tail) {
      int i = head + (nb << 2) + lane;
      float y = a[i];
      float z = ((float)(i + 1) * invL - mean) * inv_std;
      float r = expf(-0.5f * z * z) * inv_norm;
      sr += r; syr = fmaf(y, r, syr); srr = fmaf(r, r, srr);
    }
    for (int q = lane; q < nb; q += 128) {
      float4 v0 = a4[q];
      int q1 = q + 64;
      bool g1 = q1 < nb;
      float4 v1;
      if (g1) v1 = a4[q1];
      {
        float z0 = ((float)(head + (q << 2) + 1) * invL - mean) * inv_std;
        float z1 = z0 + dz, z2 = z1 + dz, z3 = z2 + dz;
        float r0 = expf(-0.5f * z0 * z0) * inv_norm;
        float r1 = expf(-0.5f * z1 * z1) * inv_norm;
        float r2 = expf(-0.5f * z2 * z2) * inv_norm;
        float r3 = expf(-0.5f * z3 * z3) * inv_norm;
        sr += (r0 + r1) + (r2 + r3);
        syr = fmaf(v0.x, r0, fmaf(v0.y, r1, fmaf(v0.z, r2, fmaf(v0.w, r3, syr))));
        srr = fmaf(r0, r0, fmaf(r1, r1, fmaf(r2, r2, fmaf(r3, r3, srr))));
      }
      if (g1) {
        float z0 = ((float)(head + (q1 << 2) + 1) * invL - mean) * inv_std;
        float z1 = z0 + dz, z2 = z1 + dz, z3 = z2 + dz;
        float r0 = expf(-0.5f * z0 * z0) * inv_norm;
        float r1 = expf(-0.5f * z1 * z1) * inv_norm;
        float r2 = expf(-0.5f * z2 * z2) * inv_norm;
        float r3 = expf(-0.5f * z3 * z3) * inv_norm;
        sr += (r0 + r1) + (r2 + r3);
        syr = fmaf(v1.x, r0, fmaf(v1.y, r1, fmaf(v1.z, r2, fmaf(v1.w, r3, syr))));
        srr = fmaf(r0, r0, fmaf(r1, r1, fmaf(r2, r2, fmaf(r3, r3, srr))));
      }
    }
#pragma unroll
    for (int off = 32; off; off >>= 1) {
      syy += __shfl_xor(syy, off, 64);
      sr  += __shfl_xor(sr, off, 64);
      syr += __shfl_xor(syr, off, 64);
      srr += __shfl_xor(srr, off, 64);
    }
    if (lane == 0) {
      float inv_den = 1.0f / (sr + 1e-6f);
      float d2 = syy - 2.0f * syr * inv_den + srr * (inv_den * inv_den);
      segpart[wid] = d2 * invL;
    }
  } else if (bid < segBlocks + L1_BLOCKS) {
    // ---------------- L1: per-wave partials, no barriers --------------------
    int b = bid - segBlocks;
    const float4* p4 = (const float4*)params;
    int n4 = P >> 2;
    float s = 0.f;
    for (int i = (b << 8) + tid; i < n4; i += (L1_BLOCKS << 8)) {
      float4 v = p4[i];
      s += (fabsf(v.x) + fabsf(v.y)) + (fabsf(v.z) + fabsf(v.w));
    }
    if (b == 0) {  // tail (empty when P % 4 == 0)
      for (int i = (n4 << 2) + tid; i < P; i += 256) s += fabsf(params[i]);
    }
#pragma unroll
    for (int off = 32; off; off >>= 1) s += __shfl_xor(s, off, 64);
    if (lane == 0) l1part[(b << 2) + wv] = s;
  } else {
    // ---------------- NLL: per-wave partials --------------------------------
    const float2* lg2 = (const float2*)logits;
    float s = 0.f;
    for (int r = tid; r < Bn; r += 256) {
      float2 lg = lg2[r];
      float m = fmaxf(lg.x, lg.y);
      float lse = m + logf(expf(lg.x - m) + expf(lg.y - m));
      s += lse - ((labels[r] == 1) ? lg.y : lg.x);
    }
#pragma unroll
    for (int off = 32; off; off >>= 1) s += __shfl_xor(s, off, 64);
    if (lane == 0) nllpart[wv] = s;
  }
}

// ---- finalize: one 256-thread block, f64 accumulation ----------------------
__global__ __launch_bounds__(256) void final_kernel(
    const float* __restrict__ segpart, const float* __restrict__ l1part,
    const float* __restrict__ nllpart, float* __restrict__ out, int Bn) {
  __shared__ double sA[4], sB[4], sC[4];
  int tid = threadIdx.x, lane = tid & 63, wv = tid >> 6;
  double accS = 0.0, accL = 0.0, accN = 0.0;
  const float4* s4 = (const float4*)segpart;
  for (int i = tid; i < (Bn >> 2); i += 256) {
    float4 v = s4[i];
    accS += ((double)v.x + (double)v.y) + ((double)v.z + (double)v.w);
  }
  for (int i = (Bn & ~3) + tid; i < Bn; i += 256) accS += (double)segpart[i];
  const float4* l4 = (const float4*)l1part;
  for (int i = tid; i < L1_BLOCKS; i += 256) {  // L1_BLOCKS*4 floats = L1_BLOCKS quads
    float4 v = l4[i];
    accL += ((double)v.x + (double)v.y) + ((double)v.z + (double)v.w);
  }
  if (tid < 4) accN = (double)nllpart[tid];
#pragma unroll
  for (int off = 32; off; off >>= 1) {
    accS += __shfl_down(accS, off, 64);
    accL += __shfl_down(accL, off, 64);
    accN += __shfl_down(accN, off, 64);
  }
  if (lane == 0) { sA[wv] = accS; sB[wv] = accL; sC[wv] = accN; }
  __syncthreads();
  if (tid == 0) {
    double segsum = (sA[0] + sA[1]) + (sA[2] + sA[3]);
    double l1     = (sB[0] + sB[1]) + (sB[2] + sB[3]);
    double nllsum = (sC[0] + sC[1]) + (sC[2] + sC[3]);
    double nll = nllsum / (double)Bn;
    double loss = nll + 5e-4 * l1 + 0.05 * (segsum / (double)Bn);
    out[0] = (float)loss;
    out[1] = (float)nll;
  }
}

extern "C" void kernel_launch(void* const* d_in, const int* in_sizes, int n_in,
                              void* d_out, int out_size, void* d_ws, size_t ws_size,
                              hipStream_t stream) {
  const float* logits  = (const float*)d_in[0];
  const float* params  = (const float*)d_in[1];
  const float* attn    = (const float*)d_in[2];
  const int*   labels  = (const int*)d_in[3];
  const int*   lengths = (const int*)d_in[4];
  // d_in[5] (seg_ids) unused: starts recomputed per wave from lengths.

  int Bn = in_sizes[3];
  int P  = in_sizes[1];
  int segBlocks = (Bn + 3) / 4;

  float* segpart = (float*)d_ws;
  float* l1part  = (float*)((char*)d_ws + 16384);
  float* nllpart = (float*)((char*)d_ws + 24576);

  int grid = segBlocks + L1_BLOCKS + 1;
  hipLaunchKernelGGL(main_kernel, dim3(grid), dim3(256), 0, stream,
                     logits, params, attn, labels, lengths, P, Bn, segBlocks,
                     segpart, l1part, nllpart);
  hipLaunchKernelGGL(final_kernel, dim3(1), dim3(256), 0, stream,
                     segpart, l1part, nllpart, (float*)d_out, Bn);
}

// Round 6
// 114.276 us; speedup vs baseline: 2.4174x; 1.0150x over previous
//
#include <hip/hip_runtime.h>

// ---------------------------------------------------------------------------
// GuidedAttentionL1Loss on MI355X — R5: R4 structure + deeper load pipeline.
// loss = nll + (ALPHA/2)*sum|params| + (BETA/2)*mean_b( sum_b (y-r)^2 / L_b )
// sum(y-r)^2 = sum y^2 - 2*sum(y*rh)/den + sum(rh^2)/den^2, den = sum(rh)+1e-6
// rh_i = inv_norm * e_i, e_i = exp2(C * z_i^2): accumulate e-sums only,
// fold inv_norm into the closing algebra (saves muls in the hot exp loop).
// vs R4: 4-deep float4 pipelining (was 2), exp2f path, inv_norm hoisted.
// Wave-per-segment, no barriers/LDS/atomics in hot path (R1/R4 lesson:
// every coupling structure — counter-fence, LDS staging, reg-array — lost).
// ---------------------------------------------------------------------------

constexpr float INV_SQRT_2PI = 0.39894228040143267794f;
constexpr float NEG_HALF_LOG2E = -0.72134752044448170368f;  // -0.5*log2(e)
constexpr int L1_BLOCKS = 512;

// ws layout (bytes) — every slot written before read, no zeroing needed:
//   0:     float segpart[4096]
//   16384: float l1part[L1_BLOCKS*4]
//   24576: float nllpart[4]

__global__ __launch_bounds__(256) void main_kernel(
    const float* __restrict__ logits, const float* __restrict__ params,
    const float* __restrict__ attn, const int* __restrict__ labels,
    const int* __restrict__ lengths, int P, int Bn, int segBlocks,
    float* __restrict__ segpart, float* __restrict__ l1part,
    float* __restrict__ nllpart) {
  const int tid = threadIdx.x, lane = tid & 63, wv = tid >> 6;
  const int bid = blockIdx.x;

  if (bid < segBlocks) {
    // ---------------- segment penalty: one wave per segment, no barriers ----
    int wid = (bid << 2) + wv;
    if (wid >= Bn) return;

    // exclusive start = sum lengths[0..wid) via int4 mini-scan (L2-hot)
    int sacc = 0;
    const int4* l4 = (const int4*)lengths;
    int nq = wid >> 2;
    for (int q = lane; q < nq; q += 64) {
      int4 v = l4[q];
      sacc += (v.x + v.y) + (v.z + v.w);
    }
    if (lane < (wid & 3)) sacc += lengths[(wid & ~3) + lane];
#pragma unroll
    for (int off = 32; off; off >>= 1) sacc += __shfl_xor(sacc, off, 64);
    int start = sacc;
    int L = lengths[wid];
    int lab = labels[wid];

    const float* a = attn + start;
    float invL = 1.0f / (float)L;
    int head = (4 - (start & 3)) & 3;   // peel to 16B alignment
    if (head > L) head = L;
    int nb = (L - head) >> 2;           // aligned float4 quads (<= 768)
    int tail = L - head - (nb << 2);
    const float4* a4 = (const float4*)(a + head);

    // ---- pass A: y-moments, 4-deep float4 pipeline ----
    float sy = 0.f, sxy = 0.f, syy = 0.f;
    auto momA = [&](const float4& v, int q) {
      float x0 = (float)(head + (q << 2) + 1) * invL;
      sy += (v.x + v.y) + (v.z + v.w);
      sxy = fmaf(x0, v.x, fmaf(x0 + invL, v.y,
            fmaf(x0 + 2.f * invL, v.z, fmaf(x0 + 3.f * invL, v.w, sxy))));
      syy = fmaf(v.x, v.x, fmaf(v.y, v.y, fmaf(v.z, v.z, fmaf(v.w, v.w, syy))));
    };
    if (lane < head) {
      float y = a[lane];
      float x = (float)(lane + 1) * invL;
      sy += y; sxy = fmaf(x, y, sxy); syy = fmaf(y, y, syy);
    }
    if (lane < tail) {
      int i = head + (nb << 2) + lane;
      float y = a[i];
      float x = (float)(i + 1) * invL;
      sy += y; sxy = fmaf(x, y, sxy); syy = fmaf(y, y, syy);
    }
    for (int q = lane; q < nb; q += 256) {
      int q1 = q + 64, q2 = q + 128, q3 = q + 192;
      bool g1 = q1 < nb, g2 = q2 < nb, g3 = q3 < nb;
      float4 v0 = a4[q];
      float4 v1, v2, v3;
      if (g1) v1 = a4[q1];
      if (g2) v2 = a4[q2];
      if (g3) v3 = a4[q3];
      momA(v0, q);
      if (g1) momA(v1, q1);
      if (g2) momA(v2, q2);
      if (g3) momA(v3, q3);
    }
#pragma unroll
    for (int off = 32; off; off >>= 1) {
      sy  += __shfl_xor(sy, off, 64);
      sxy += __shfl_xor(sxy, off, 64);
    }
    float mean = sxy / sy;
    float inv_std = (lab == 1) ? (float)L : (float)L * 0.001f;
    float dz = invL * inv_std;

    // ---- pass B: re-read y (L2/L3-hot), e-moments (inv_norm hoisted) ----
    // e = exp2(NEG_HALF_LOG2E * z^2); rh = inv_norm * e
    float se = 0.f, sye = 0.f, see = 0.f;
    auto momB = [&](const float4& v, int q) {
      float z0 = ((float)(head + (q << 2) + 1) * invL - mean) * inv_std;
      float z1 = z0 + dz, z2 = z1 + dz, z3 = z2 + dz;
      float e0 = exp2f(z0 * z0 * NEG_HALF_LOG2E);
      float e1 = exp2f(z1 * z1 * NEG_HALF_LOG2E);
      float e2 = exp2f(z2 * z2 * NEG_HALF_LOG2E);
      float e3 = exp2f(z3 * z3 * NEG_HALF_LOG2E);
      se += (e0 + e1) + (e2 + e3);
      sye = fmaf(v.x, e0, fmaf(v.y, e1, fmaf(v.z, e2, fmaf(v.w, e3, sye))));
      see = fmaf(e0, e0, fmaf(e1, e1, fmaf(e2, e2, fmaf(e3, e3, see))));
    };
    if (lane < head) {
      float y = a[lane];
      float z = ((float)(lane + 1) * invL - mean) * inv_std;
      float e = exp2f(z * z * NEG_HALF_LOG2E);
      se += e; sye = fmaf(y, e, sye); see = fmaf(e, e, see);
    }
    if (lane < tail) {
      int i = head + (nb << 2) + lane;
      float y = a[i];
      float z = ((float)(i + 1) * invL - mean) * inv_std;
      float e = exp2f(z * z * NEG_HALF_LOG2E);
      se += e; sye = fmaf(y, e, sye); see = fmaf(e, e, see);
    }
    for (int q = lane; q < nb; q += 256) {
      int q1 = q + 64, q2 = q + 128, q3 = q + 192;
      bool g1 = q1 < nb, g2 = q2 < nb, g3 = q3 < nb;
      float4 v0 = a4[q];
      float4 v1, v2, v3;
      if (g1) v1 = a4[q1];
      if (g2) v2 = a4[q2];
      if (g3) v3 = a4[q3];
      momB(v0, q);
      if (g1) momB(v1, q1);
      if (g2) momB(v2, q2);
      if (g3) momB(v3, q3);
    }
#pragma unroll
    for (int off = 32; off; off >>= 1) {
      syy += __shfl_xor(syy, off, 64);
      se  += __shfl_xor(se, off, 64);
      sye += __shfl_xor(sye, off, 64);
      see += __shfl_xor(see, off, 64);
    }
    if (lane == 0) {
      float inv_norm = INV_SQRT_2PI * inv_std;
      float den = fmaf(inv_norm, se, 1e-6f);     // sum(rh) + 1e-6
      float inv_den = 1.0f / den;
      float c = inv_norm * inv_den;               // rh/den scale for e-sums
      float d2 = syy - 2.0f * sye * c + see * (c * c);
      segpart[wid] = d2 * invL;
    }
  } else if (bid < segBlocks + L1_BLOCKS) {
    // ---------------- L1: per-wave partials, no barriers --------------------
    int b = bid - segBlocks;
    const float4* p4 = (const float4*)params;
    int n4 = P >> 2;
    float s = 0.f;
    for (int i = (b << 8) + tid; i < n4; i += (L1_BLOCKS << 8)) {
      float4 v = p4[i];
      s += (fabsf(v.x) + fabsf(v.y)) + (fabsf(v.z) + fabsf(v.w));
    }
    if (b == 0) {  // tail (empty when P % 4 == 0)
      for (int i = (n4 << 2) + tid; i < P; i += 256) s += fabsf(params[i]);
    }
#pragma unroll
    for (int off = 32; off; off >>= 1) s += __shfl_xor(s, off, 64);
    if (lane == 0) l1part[(b << 2) + wv] = s;
  } else {
    // ---------------- NLL: per-wave partials --------------------------------
    const float2* lg2 = (const float2*)logits;
    float s = 0.f;
    for (int r = tid; r < Bn; r += 256) {
      float2 lg = lg2[r];
      float m = fmaxf(lg.x, lg.y);
      float lse = m + logf(expf(lg.x - m) + expf(lg.y - m));
      s += lse - ((labels[r] == 1) ? lg.y : lg.x);
    }
#pragma unroll
    for (int off = 32; off; off >>= 1) s += __shfl_xor(s, off, 64);
    if (lane == 0) nllpart[wv] = s;
  }
}

// ---- finalize: one 256-thread block, f64 accumulation ----------------------
__global__ __launch_bounds__(256) void final_kernel(
    const float* __restrict__ segpart, const float* __restrict__ l1part,
    const float* __restrict__ nllpart, float* __restrict__ out, int Bn) {
  __shared__ double sA[4], sB[4], sC[4];
  int tid = threadIdx.x, lane = tid & 63, wv = tid >> 6;
  double accS = 0.0, accL = 0.0, accN = 0.0;
  const float4* s4 = (const float4*)segpart;
  for (int i = tid; i < (Bn >> 2); i += 256) {
    float4 v = s4[i];
    accS += ((double)v.x + (double)v.y) + ((double)v.z + (double)v.w);
  }
  for (int i = (Bn & ~3) + tid; i < Bn; i += 256) accS += (double)segpart[i];
  const float4* l4 = (const float4*)l1part;
  for (int i = tid; i < L1_BLOCKS; i += 256) {
    float4 v = l4[i];
    accL += ((double)v.x + (double)v.y) + ((double)v.z + (double)v.w);
  }
  if (tid < 4) accN = (double)nllpart[tid];
#pragma unroll
  for (int off = 32; off; off >>= 1) {
    accS += __shfl_down(accS, off, 64);
    accL += __shfl_down(accL, off, 64);
    accN += __shfl_down(accN, off, 64);
  }
  if (lane == 0) { sA[wv] = accS; sB[wv] = accL; sC[wv] = accN; }
  __syncthreads();
  if (tid == 0) {
    double segsum = (sA[0] + sA[1]) + (sA[2] + sA[3]);
    double l1     = (sB[0] + sB[1]) + (sB[2] + sB[3]);
    double nllsum = (sC[0] + sC[1]) + (sC[2] + sC[3]);
    double nll = nllsum / (double)Bn;
    double loss = nll + 5e-4 * l1 + 0.05 * (segsum / (double)Bn);
    out[0] = (float)loss;
    out[1] = (float)nll;
  }
}

extern "C" void kernel_launch(void* const* d_in, const int* in_sizes, int n_in,
                              void* d_out, int out_size, void* d_ws, size_t ws_size,
                              hipStream_t stream) {
  const float* logits  = (const float*)d_in[0];
  const float* params  = (const float*)d_in[1];
  const float* attn    = (const float*)d_in[2];
  const int*   labels  = (const int*)d_in[3];
  const int*   lengths = (const int*)d_in[4];
  // d_in[5] (seg_ids) unused: starts recomputed per wave from lengths.

  int Bn = in_sizes[3];
  int P  = in_sizes[1];
  int segBlocks = (Bn + 3) / 4;

  float* segpart = (float*)d_ws;
  float* l1part  = (float*)((char*)d_ws + 16384);
  float* nllpart = (float*)((char*)d_ws + 24576);

  int grid = segBlocks + L1_BLOCKS + 1;
  hipLaunchKernelGGL(main_kernel, dim3(grid), dim3(256), 0, stream,
                     logits, params, attn, labels, lengths, P, Bn, segBlocks,
                     segpart, l1part, nllpart);
  hipLaunchKernelGGL(final_kernel, dim3(1), dim3(256), 0, stream,
                     segpart, l1part, nllpart, (float*)d_out, Bn);
}